// Round 6
// baseline (305.503 us; speedup 1.0000x reference)
//
#include <hip/hip_runtime.h>
#include <hip/hip_bf16.h>
#include <stdint.h>

typedef __attribute__((ext_vector_type(8))) short bf16x8;   // 8 bf16 (4 VGPRs)
typedef __attribute__((ext_vector_type(4))) short s16x4;
typedef __attribute__((ext_vector_type(4))) float f32x4;

#define MFMA16(a, b, c) __builtin_amdgcn_mfma_f32_16x16x32_bf16((a), (b), (c), 0, 0, 0)
// v_mfma_f32_16x16x16_bf16 (cdna4_isa §10: A=2 regs, B=2 regs, C/D=4) — the
// ROCm builtin keeps the gfx90a "_1k" name. Do NOT guard with __has_builtin
// (returns false in the host pass and breaks the build — round 5 lesson).
#define MFMAH(a, b, c) __builtin_amdgcn_mfma_f32_16x16x16bf16_1k((a), (b), (c), 0, 0, 0)

__device__ __forceinline__ void gload_lds16(const void* g, void* l) {
  // async global->LDS, 16B/lane; LDS dest = wave-uniform base + lane*16
  __builtin_amdgcn_global_load_lds((const __attribute__((address_space(1))) void*)g,
                                   (__attribute__((address_space(3))) void*)l, 16, 0, 0);
}

// ---- f32 -> bf16 bulk convert (n divisible by 4) ----
__global__ void f32_to_bf16(const float* __restrict__ in, __hip_bfloat16* __restrict__ out, int n) {
  const int i = (blockIdx.x * blockDim.x + threadIdx.x) * 4;
  if (i + 3 < n) {
    const float4 v = *(const float4*)(in + i);
    s16x4 o;
    __hip_bfloat16 h;
    h = __float2bfloat16(v.x); o[0] = *(short*)&h;
    h = __float2bfloat16(v.y); o[1] = *(short*)&h;
    h = __float2bfloat16(v.z); o[2] = *(short*)&h;
    h = __float2bfloat16(v.w); o[3] = *(short*)&h;
    *(s16x4*)((short*)out + i) = o;
  }
}

// C[M,N] = A[M,K] @ W[N,K]^T + bias, optional ReLU. 128x128 tile, BK=32, 4 waves.
// OUTMODE: 0 = bf16 row-major [M][N]; 1 = f32 row-major; 2 = bf16 V^T layout
//          [b*16+h][d][s] (b=row>>8, s=row&255, h=col>>6, d=col&63).
template <int RELU, int OUTMODE>
__global__ __launch_bounds__(256, 2) void gemm_bt(
    const __hip_bfloat16* __restrict__ Abf, const __hip_bfloat16* __restrict__ Wbf,
    const float* __restrict__ bias, void* __restrict__ Cv,
    int M, int N, int K) {
  __shared__ __align__(16) __hip_bfloat16 As[128 * 32];
  __shared__ __align__(16) __hip_bfloat16 Bs[128 * 32];
  const int t = threadIdx.x;
  const int w = t >> 6, lane = t & 63;
  const int lr = lane & 15, lg = lane >> 4;
  const int m0 = blockIdx.x * 128, n0 = blockIdx.y * 128;
  const int wr = (w >> 1) * 64, wc = (w & 1) * 64;

  const char* Ag = (const char*)Abf;
  const char* Wg = (const char*)Wbf;
  const size_t ldb = (size_t)K * 2;  // row bytes

  f32x4 acc[4][4] = {};

  const int o0 = (w << 10) + lane * 16;
  const int o1 = o0 + 4096;
  const int r0 = o0 >> 6, c0 = o0 & 63;
  const int r1 = o1 >> 6, c1 = o1 & 63;

  for (int kt = 0; kt < K; kt += 32) {
    if (kt) __syncthreads();
    gload_lds16(Ag + (size_t)(m0 + r0) * ldb + kt * 2 + c0, (char*)As + (w << 10));
    gload_lds16(Ag + (size_t)(m0 + r1) * ldb + kt * 2 + c1, (char*)As + 4096 + (w << 10));
    gload_lds16(Wg + (size_t)(n0 + r0) * ldb + kt * 2 + c0, (char*)Bs + (w << 10));
    gload_lds16(Wg + (size_t)(n0 + r1) * ldb + kt * 2 + c1, (char*)Bs + 4096 + (w << 10));
    __syncthreads();

    bf16x8 af[4], bfv[4];
#pragma unroll
    for (int mi = 0; mi < 4; ++mi)
      af[mi] = *(const bf16x8*)((const char*)As + ((wr + mi * 16 + lr) << 6) + (lg << 4));
#pragma unroll
    for (int ni = 0; ni < 4; ++ni)
      bfv[ni] = *(const bf16x8*)((const char*)Bs + ((wc + ni * 16 + lr) << 6) + (lg << 4));
#pragma unroll
    for (int mi = 0; mi < 4; ++mi)
#pragma unroll
      for (int ni = 0; ni < 4; ++ni)
        acc[mi][ni] = MFMA16(af[mi], bfv[ni], acc[mi][ni]);
  }

#pragma unroll
  for (int ni = 0; ni < 4; ++ni) {
    const int col = n0 + wc + ni * 16 + lr;
    const float bv = bias[col];
#pragma unroll
    for (int mi = 0; mi < 4; ++mi) {
      const int row = m0 + wr + mi * 16 + lg * 4;
#pragma unroll
      for (int j = 0; j < 4; ++j) {
        float v = acc[mi][ni][j] + bv;
        if (RELU) v = fmaxf(v, 0.0f);
        if (OUTMODE == 0) {
          ((__hip_bfloat16*)Cv)[(size_t)(row + j) * N + col] = __float2bfloat16(v);
        } else if (OUTMODE == 1) {
          ((float*)Cv)[(size_t)(row + j) * N + col] = v;
        } else {
          const int rb = (row + j) >> 8, s = (row + j) & 255;
          const int hh = col >> 6, d = col & 63;
          ((__hip_bfloat16*)Cv)[(((size_t)(rb * 16 + hh) * 64 + d) << 8) + s] =
              __float2bfloat16(v);
        }
      }
    }
  }
}

// Fused cross-attention v2: swapped QK^T, register-resident P (16x16x16 PV),
// K/V^T staged once per 256 q-rows via pre-swizzled global_load_lds.
// Block = (256 q-rows, head h, batch b), 4 waves; 4 q-subtile iterations.
// LDS: Vt [64d][256s] swz ^((d&7)<<4) | Ks [256s][64d] swz ^((s&7)<<4) = 64KB.
__global__ __launch_bounds__(256, 2) void attn_fused(
    const __hip_bfloat16* __restrict__ Qb, const __hip_bfloat16* __restrict__ Kb,
    const __hip_bfloat16* __restrict__ Vtg, const float* __restrict__ padm,
    const float* __restrict__ seqm, __hip_bfloat16* __restrict__ O) {
  constexpr int S = 256, E = 1024, Nq = 4096;
  constexpr float NEGV = -1e9f;
  __shared__ __align__(16) char smem[65536];
  char* VtB = smem;
  char* KsB = smem + 32768;

  const int t = threadIdx.x;
  const int w = t >> 6, lane = t & 63;
  const int lr = lane & 15, lg = lane >> 4;
  const int qc = blockIdx.x, h = blockIdx.y, b = blockIdx.z;

  // --- stage K [256s][64d]: linear LDS dest + inverse-swizzled source ---
  const char* Kg = (const char*)(Kb + (size_t)b * S * E + h * 64);
#pragma unroll
  for (int i = 0; i < 8; ++i) {
    const int o = ((i * 4 + w) << 10) + lane * 16;
    const int s = o >> 7, bc = o & 127;
    gload_lds16(Kg + (size_t)s * (E * 2) + (bc ^ ((s & 7) << 4)), KsB + ((i * 4 + w) << 10));
  }
  // --- stage V^T [64d][256s] from pre-transposed global ---
  const char* Vg = (const char*)Vtg + ((size_t)(b * 16 + h) << 15);
#pragma unroll
  for (int i = 0; i < 8; ++i) {
    const int o = ((i * 4 + w) << 10) + lane * 16;
    const int d = o >> 9, c = o & 511;
    gload_lds16(Vg + (d << 9) + (c ^ ((d & 7) << 4)), VtB + ((i * 4 + w) << 10));
  }
  __syncthreads();  // only barrier in the kernel; waves desync afterwards

  const int swz = (lr & 7) << 4;

  for (int it = 0; it < 4; ++it) {
    const int qw = qc * 256 + it * 64 + w * 16;
    const short* Qg = (const short*)Qb + (size_t)(b * Nq + qw + lr) * E + h * 64;
    const bf16x8 aq0 = *(const bf16x8*)(Qg + (lg << 3));
    const bf16x8 aq1 = *(const bf16x8*)(Qg + 32 + (lg << 3));
    const float padq = padm[(size_t)b * Nq + qw + lr];
    const float qbias = (padq != 0.f) ? 0.f : NEGV;

    f32x4 o[4] = {};
    float ssum = 0.f;
#pragma unroll
    for (int ni = 0; ni < 16; ++ni) {
      // QK^T swapped: A=K-frag (s rows), B=Q-frag -> D[s=lg*4+j][q=lr]
      const int s = ni * 16 + lr;
      const bf16x8 bk0 = *(const bf16x8*)(KsB + (s << 7) + ((lg << 4) ^ swz));
      const bf16x8 bk1 = *(const bf16x8*)(KsB + (s << 7) + ((64 + (lg << 4)) ^ swz));
      f32x4 a = {};
      a = MFMA16(bk0, aq0, a);
      a = MFMA16(bk1, aq1, a);

      // mask (additive bias) + exp; no max-subtract (|score*scale| < ~4)
      const float4 sm4 = *(const float4*)(seqm + (size_t)b * S + ni * 16 + lg * 4);
      const float e0 = __expf(a[0] * 0.125f + ((sm4.x != 0.f ? 0.f : NEGV) + qbias));
      const float e1 = __expf(a[1] * 0.125f + ((sm4.y != 0.f ? 0.f : NEGV) + qbias));
      const float e2 = __expf(a[2] * 0.125f + ((sm4.z != 0.f ? 0.f : NEGV) + qbias));
      const float e3 = __expf(a[3] * 0.125f + ((sm4.w != 0.f ? 0.f : NEGV) + qbias));
      ssum += (e0 + e1) + (e2 + e3);

      // P fragment stays in registers: D-layout == A-frag of 16x16x16 MFMA
      s16x4 pf;
      __hip_bfloat16 hh;
      hh = __float2bfloat16(e0); pf[0] = *(short*)&hh;
      hh = __float2bfloat16(e1); pf[1] = *(short*)&hh;
      hh = __float2bfloat16(e2); pf[2] = *(short*)&hh;
      hh = __float2bfloat16(e3); pf[3] = *(short*)&hh;

      // PV: B-frag = V[s=ni*16+lg*4+e][d=nd*16+lr] from swizzled Vt rows
      const int sb = (ni * 32 + lg * 8);  // byte offset of s0 within a Vt row
#pragma unroll
      for (int nd = 0; nd < 4; ++nd) {
        const int d = nd * 16 + lr;  // d&7 == lr&7 -> same swz
        const s16x4 bv = *(const s16x4*)(VtB + (d << 9) + (sb ^ swz));
        o[nd] = MFMAH(pf, bv, o[nd]);
      }
    }

    // row-sum lives lane-local (q=lr); reduce over the 4 lg replicas
    ssum += __shfl_xor(ssum, 16);
    ssum += __shfl_xor(ssum, 32);
    const float inv = 1.0f / ssum;
    float invj[4];
#pragma unroll
    for (int j = 0; j < 4; ++j) invj[j] = __shfl(inv, lg * 4 + j);

    __hip_bfloat16* Og = O + (size_t)(b * Nq + qw) * E + h * 64;
#pragma unroll
    for (int nd = 0; nd < 4; ++nd)
#pragma unroll
      for (int j = 0; j < 4; ++j)
        Og[(size_t)(lg * 4 + j) * E + nd * 16 + lr] = __float2bfloat16(o[nd][j] * invj[j]);
  }
}

extern "C" void kernel_launch(void* const* d_in, const int* in_sizes, int n_in,
                              void* d_out, int out_size, void* d_ws, size_t ws_size,
                              hipStream_t stream) {
  // All reference tensors are float32.
  const float* x    = (const float*)d_in[0];
  const float* ctx  = (const float*)d_in[1];
  const float* padm = (const float*)d_in[2];
  const float* seqm = (const float*)d_in[3];
  const float* Wq_w = (const float*)d_in[4];
  const float* Wq_b = (const float*)d_in[5];
  const float* Wk_w = (const float*)d_in[6];
  const float* Wk_b = (const float*)d_in[7];
  const float* Wv_w = (const float*)d_in[8];
  const float* Wv_b = (const float*)d_in[9];
  const float* P1_w = (const float*)d_in[10];
  const float* P1_b = (const float*)d_in[11];
  const float* P2_w = (const float*)d_in[12];
  const float* P2_b = (const float*)d_in[13];
  float* out = (float*)d_out;

  char* ws = (char*)d_ws;
  size_t off = 0;
  auto alloc = [&](size_t bytes) { char* p = ws + off; off += (bytes + 255) & ~(size_t)255; return p; };
  __hip_bfloat16* Q    = (__hip_bfloat16*)alloc(16384ull * 1024 * 2);  // 32MB (later O1)
  __hip_bfloat16* AO   = (__hip_bfloat16*)alloc(16384ull * 1024 * 2);  // 32MB
  __hip_bfloat16* xb   = (__hip_bfloat16*)alloc(16384ull * 512 * 2);   // 16MB
  __hip_bfloat16* ctxb = (__hip_bfloat16*)alloc(1024ull * 768 * 2);
  __hip_bfloat16* Kp   = (__hip_bfloat16*)alloc(1024ull * 1024 * 2);
  __hip_bfloat16* Vt   = (__hip_bfloat16*)alloc(1024ull * 1024 * 2);   // V^T [b,h][d][s]
  __hip_bfloat16* Wqb  = (__hip_bfloat16*)alloc(1024ull * 512 * 2);
  __hip_bfloat16* Wkb  = (__hip_bfloat16*)alloc(1024ull * 768 * 2);
  __hip_bfloat16* Wvb  = (__hip_bfloat16*)alloc(1024ull * 768 * 2);
  __hip_bfloat16* P1b  = (__hip_bfloat16*)alloc(1024ull * 1024 * 2);
  __hip_bfloat16* P2b  = (__hip_bfloat16*)alloc(512ull * 1024 * 2);
  __hip_bfloat16* O1   = Q;  // reuse Q after attention

  const dim3 blk(256, 1, 1);
  auto cvt = [&](const float* src, __hip_bfloat16* dst, int n) {
    f32_to_bf16<<<dim3((n + 1023) / 1024, 1, 1), blk, 0, stream>>>(src, dst, n);
  };
  cvt(x,    xb,   16384 * 512);
  cvt(ctx,  ctxb, 1024 * 768);
  cvt(Wq_w, Wqb,  1024 * 512);
  cvt(Wk_w, Wkb,  1024 * 768);
  cvt(Wv_w, Wvb,  1024 * 768);
  cvt(P1_w, P1b,  1024 * 1024);
  cvt(P2_w, P2b,  512 * 1024);

  gemm_bt<0, 0><<<dim3(128, 8, 1), blk, 0, stream>>>(xb,   Wqb, Wq_b, Q,   16384, 1024, 512);
  gemm_bt<0, 0><<<dim3(8, 8, 1),   blk, 0, stream>>>(ctxb, Wkb, Wk_b, Kp,  1024, 1024, 768);
  gemm_bt<0, 2><<<dim3(8, 8, 1),   blk, 0, stream>>>(ctxb, Wvb, Wv_b, Vt,  1024, 1024, 768);
  attn_fused<<<dim3(16, 16, 4), blk, 0, stream>>>(Q, Kp, Vt, padm, seqm, AO);
  gemm_bt<1, 0><<<dim3(128, 8, 1), blk, 0, stream>>>(AO, P1b, P1_b, O1,  16384, 1024, 1024);
  gemm_bt<0, 1><<<dim3(128, 4, 1), blk, 0, stream>>>(O1, P2b, P2_b, out, 16384, 512, 1024);
}

// Round 7
// 209.437 us; speedup vs baseline: 1.4587x; 1.4587x over previous
//
#include <hip/hip_runtime.h>
#include <hip/hip_bf16.h>
#include <stdint.h>

typedef __attribute__((ext_vector_type(8))) short bf16x8;   // 8 bf16 (4 VGPRs)
typedef __attribute__((ext_vector_type(4))) short s16x4;
typedef __attribute__((ext_vector_type(4))) float f32x4;

#define MFMA16(a, b, c) __builtin_amdgcn_mfma_f32_16x16x32_bf16((a), (b), (c), 0, 0, 0)
// v_mfma_f32_16x16x16_bf16 — ROCm builtin keeps the gfx90a "_1k" name.
#define MFMAH(a, b, c) __builtin_amdgcn_mfma_f32_16x16x16bf16_1k((a), (b), (c), 0, 0, 0)

__device__ __forceinline__ void gload_lds16(const void* g, void* l) {
  __builtin_amdgcn_global_load_lds((const __attribute__((address_space(1))) void*)g,
                                   (__attribute__((address_space(3))) void*)l, 16, 0, 0);
}

// ---- f32 -> bf16 bulk convert (n divisible by 4) ----
__global__ void f32_to_bf16(const float* __restrict__ in, __hip_bfloat16* __restrict__ out, int n) {
  const int i = (blockIdx.x * blockDim.x + threadIdx.x) * 4;
  if (i + 3 < n) {
    const float4 v = *(const float4*)(in + i);
    s16x4 o;
    __hip_bfloat16 h;
    h = __float2bfloat16(v.x); o[0] = *(short*)&h;
    h = __float2bfloat16(v.y); o[1] = *(short*)&h;
    h = __float2bfloat16(v.z); o[2] = *(short*)&h;
    h = __float2bfloat16(v.w); o[3] = *(short*)&h;
    *(s16x4*)((short*)out + i) = o;
  }
}

// C[M,N] = A[M,K] @ W[N,K]^T + bias, optional ReLU. 128x128 tile, BK=32, 4 waves.
// OUTMODE: 0 = bf16 row-major; 1 = f32 row-major; 2 = bf16 V^T layout
//          [b*16+h][d][s] (b=row>>8, s=row&255, h=col>>6, d=col&63).
template <int RELU, int OUTMODE>
__global__ __launch_bounds__(256, 2) void gemm_bt(
    const __hip_bfloat16* __restrict__ Abf, const __hip_bfloat16* __restrict__ Wbf,
    const float* __restrict__ bias, void* __restrict__ Cv,
    int M, int N, int K) {
  __shared__ __align__(16) __hip_bfloat16 As[128 * 32];
  __shared__ __align__(16) __hip_bfloat16 Bs[128 * 32];
  const int t = threadIdx.x;
  const int w = t >> 6, lane = t & 63;
  const int lr = lane & 15, lg = lane >> 4;
  const int m0 = blockIdx.x * 128, n0 = blockIdx.y * 128;
  const int wr = (w >> 1) * 64, wc = (w & 1) * 64;

  const char* Ag = (const char*)Abf;
  const char* Wg = (const char*)Wbf;
  const size_t ldb = (size_t)K * 2;

  f32x4 acc[4][4] = {};

  const int o0 = (w << 10) + lane * 16;
  const int o1 = o0 + 4096;
  const int r0 = o0 >> 6, c0 = o0 & 63;
  const int r1 = o1 >> 6, c1 = o1 & 63;

  for (int kt = 0; kt < K; kt += 32) {
    if (kt) __syncthreads();
    gload_lds16(Ag + (size_t)(m0 + r0) * ldb + kt * 2 + c0, (char*)As + (w << 10));
    gload_lds16(Ag + (size_t)(m0 + r1) * ldb + kt * 2 + c1, (char*)As + 4096 + (w << 10));
    gload_lds16(Wg + (size_t)(n0 + r0) * ldb + kt * 2 + c0, (char*)Bs + (w << 10));
    gload_lds16(Wg + (size_t)(n0 + r1) * ldb + kt * 2 + c1, (char*)Bs + 4096 + (w << 10));
    __syncthreads();

    bf16x8 af[4], bfv[4];
#pragma unroll
    for (int mi = 0; mi < 4; ++mi)
      af[mi] = *(const bf16x8*)((const char*)As + ((wr + mi * 16 + lr) << 6) + (lg << 4));
#pragma unroll
    for (int ni = 0; ni < 4; ++ni)
      bfv[ni] = *(const bf16x8*)((const char*)Bs + ((wc + ni * 16 + lr) << 6) + (lg << 4));
#pragma unroll
    for (int mi = 0; mi < 4; ++mi)
#pragma unroll
      for (int ni = 0; ni < 4; ++ni)
        acc[mi][ni] = MFMA16(af[mi], bfv[ni], acc[mi][ni]);
  }

#pragma unroll
  for (int ni = 0; ni < 4; ++ni) {
    const int col = n0 + wc + ni * 16 + lr;
    const float bv = bias[col];
#pragma unroll
    for (int mi = 0; mi < 4; ++mi) {
      const int row = m0 + wr + mi * 16 + lg * 4;
#pragma unroll
      for (int j = 0; j < 4; ++j) {
        float v = acc[mi][ni][j] + bv;
        if (RELU) v = fmaxf(v, 0.0f);
        if (OUTMODE == 0) {
          ((__hip_bfloat16*)Cv)[(size_t)(row + j) * N + col] = __float2bfloat16(v);
        } else if (OUTMODE == 1) {
          ((float*)Cv)[(size_t)(row + j) * N + col] = v;
        } else {
          const int rb = (row + j) >> 8, s = (row + j) & 255;
          const int hh = col >> 6, d = col & 63;
          ((__hip_bfloat16*)Cv)[(((size_t)(rb * 16 + hh) * 64 + d) << 8) + s] =
              __float2bfloat16(v);
        }
      }
    }
  }
}

// Fused cross-attention v3: round-4 frame (64 q-rows/block, grid 4096, Q once,
// one barrier) + round-6 inner loop (swapped QK^T, register P, 16x16x16 PV,
// additive-mask softmax, no max-subtract, no P LDS round-trip).
// LDS: Vt [64d][256s] swz ^((d&7)<<4) | Ks [256s][64d] swz ^((s&7)<<4) = 64KB.
__global__ __launch_bounds__(256, 2) void attn_fused(
    const __hip_bfloat16* __restrict__ Qb, const __hip_bfloat16* __restrict__ Kb,
    const __hip_bfloat16* __restrict__ Vtg, const float* __restrict__ padm,
    const float* __restrict__ seqm, __hip_bfloat16* __restrict__ O) {
  constexpr int S = 256, E = 1024, Nq = 4096;
  constexpr float NEGV = -1e9f;
  __shared__ __align__(16) char smem[65536];
  char* VtB = smem;
  char* KsB = smem + 32768;

  const int t = threadIdx.x;
  const int w = t >> 6, lane = t & 63;
  const int lr = lane & 15, lg = lane >> 4;
  const int h = blockIdx.y, b = blockIdx.z;

  // --- stage K [256s][64d]: linear LDS dest + inverse-swizzled source ---
  const char* Kg = (const char*)(Kb + (size_t)b * S * E + h * 64);
#pragma unroll
  for (int i = 0; i < 8; ++i) {
    const int o = ((i * 4 + w) << 10) + lane * 16;
    const int s = o >> 7, bc = o & 127;
    gload_lds16(Kg + (size_t)s * (E * 2) + (bc ^ ((s & 7) << 4)), KsB + ((i * 4 + w) << 10));
  }
  // --- stage V^T [64d][256s] from pre-transposed global ---
  const char* Vg = (const char*)Vtg + ((size_t)(b * 16 + h) << 15);
#pragma unroll
  for (int i = 0; i < 8; ++i) {
    const int o = ((i * 4 + w) << 10) + lane * 16;
    const int d = o >> 9, c = o & 511;
    gload_lds16(Vg + (d << 9) + (c ^ ((d & 7) << 4)), VtB + ((i * 4 + w) << 10));
  }

  // --- Q fragments (direct from global, once per block; overlaps staging) ---
  const int qw = blockIdx.x * 64 + w * 16;
  const short* Qg = (const short*)Qb + (size_t)(b * Nq + qw + lr) * E + h * 64;
  const bf16x8 aq0 = *(const bf16x8*)(Qg + (lg << 3));
  const bf16x8 aq1 = *(const bf16x8*)(Qg + 32 + (lg << 3));
  const float padq = padm[(size_t)b * Nq + qw + lr];
  const float qbias = (padq != 0.f) ? 0.f : NEGV;

  __syncthreads();

  const int swz = (lr & 7) << 4;
  f32x4 o[4] = {};
  float ssum = 0.f;
#pragma unroll
  for (int ni = 0; ni < 16; ++ni) {
    // QK^T swapped: A=K-frag (s rows), B=Q-frag -> D[s=lg*4+j][q=lr]
    const int s = ni * 16 + lr;
    const bf16x8 bk0 = *(const bf16x8*)(KsB + (s << 7) + ((lg << 4) ^ swz));
    const bf16x8 bk1 = *(const bf16x8*)(KsB + (s << 7) + ((64 + (lg << 4)) ^ swz));
    f32x4 a = {};
    a = MFMA16(bk0, aq0, a);
    a = MFMA16(bk1, aq1, a);

    // mask (additive bias) + exp; no max-subtract (|score*scale| small)
    const float4 sm4 = *(const float4*)(seqm + (size_t)b * S + ni * 16 + lg * 4);
    const float e0 = __expf(a[0] * 0.125f + ((sm4.x != 0.f ? 0.f : NEGV) + qbias));
    const float e1 = __expf(a[1] * 0.125f + ((sm4.y != 0.f ? 0.f : NEGV) + qbias));
    const float e2 = __expf(a[2] * 0.125f + ((sm4.z != 0.f ? 0.f : NEGV) + qbias));
    const float e3 = __expf(a[3] * 0.125f + ((sm4.w != 0.f ? 0.f : NEGV) + qbias));
    ssum += (e0 + e1) + (e2 + e3);

    // P stays in registers: D-layout == A-frag of 16x16x16 MFMA
    s16x4 pf;
    __hip_bfloat16 hh;
    hh = __float2bfloat16(e0); pf[0] = *(short*)&hh;
    hh = __float2bfloat16(e1); pf[1] = *(short*)&hh;
    hh = __float2bfloat16(e2); pf[2] = *(short*)&hh;
    hh = __float2bfloat16(e3); pf[3] = *(short*)&hh;

    // PV: B-frag = V[s=ni*16+lg*4+e][d=nd*16+lr] from swizzled Vt rows
    const int sb = (ni * 32 + lg * 8);
#pragma unroll
    for (int nd = 0; nd < 4; ++nd) {
      const int d = nd * 16 + lr;  // d&7 == lr&7 -> same swz
      const s16x4 bv = *(const s16x4*)(VtB + (d << 9) + (sb ^ swz));
      o[nd] = MFMAH(pf, bv, o[nd]);
    }
  }

  // row-sum: lane-local for q=lr; reduce over the 4 lg replicas
  ssum += __shfl_xor(ssum, 16);
  ssum += __shfl_xor(ssum, 32);
  const float inv = 1.0f / ssum;
  float invj[4];
#pragma unroll
  for (int j = 0; j < 4; ++j) invj[j] = __shfl(inv, lg * 4 + j);

  __hip_bfloat16* Og = O + (size_t)(b * Nq + qw) * E + h * 64;
#pragma unroll
  for (int nd = 0; nd < 4; ++nd)
#pragma unroll
    for (int j = 0; j < 4; ++j)
      Og[(size_t)(lg * 4 + j) * E + nd * 16 + lr] = __float2bfloat16(o[nd][j] * invj[j]);
}

extern "C" void kernel_launch(void* const* d_in, const int* in_sizes, int n_in,
                              void* d_out, int out_size, void* d_ws, size_t ws_size,
                              hipStream_t stream) {
  const float* x    = (const float*)d_in[0];
  const float* ctx  = (const float*)d_in[1];
  const float* padm = (const float*)d_in[2];
  const float* seqm = (const float*)d_in[3];
  const float* Wq_w = (const float*)d_in[4];
  const float* Wq_b = (const float*)d_in[5];
  const float* Wk_w = (const float*)d_in[6];
  const float* Wk_b = (const float*)d_in[7];
  const float* Wv_w = (const float*)d_in[8];
  const float* Wv_b = (const float*)d_in[9];
  const float* P1_w = (const float*)d_in[10];
  const float* P1_b = (const float*)d_in[11];
  const float* P2_w = (const float*)d_in[12];
  const float* P2_b = (const float*)d_in[13];
  float* out = (float*)d_out;

  char* ws = (char*)d_ws;
  size_t off = 0;
  auto alloc = [&](size_t bytes) { char* p = ws + off; off += (bytes + 255) & ~(size_t)255; return p; };
  __hip_bfloat16* Q    = (__hip_bfloat16*)alloc(16384ull * 1024 * 2);  // 32MB (later O1)
  __hip_bfloat16* AO   = (__hip_bfloat16*)alloc(16384ull * 1024 * 2);  // 32MB
  __hip_bfloat16* xb   = (__hip_bfloat16*)alloc(16384ull * 512 * 2);   // 16MB
  __hip_bfloat16* ctxb = (__hip_bfloat16*)alloc(1024ull * 768 * 2);
  __hip_bfloat16* Kp   = (__hip_bfloat16*)alloc(1024ull * 1024 * 2);
  __hip_bfloat16* Vt   = (__hip_bfloat16*)alloc(1024ull * 1024 * 2);   // V^T [b,h][d][s]
  __hip_bfloat16* Wqb  = (__hip_bfloat16*)alloc(1024ull * 512 * 2);
  __hip_bfloat16* Wkb  = (__hip_bfloat16*)alloc(1024ull * 768 * 2);
  __hip_bfloat16* Wvb  = (__hip_bfloat16*)alloc(1024ull * 768 * 2);
  __hip_bfloat16* P1b  = (__hip_bfloat16*)alloc(1024ull * 1024 * 2);
  __hip_bfloat16* P2b  = (__hip_bfloat16*)alloc(512ull * 1024 * 2);
  __hip_bfloat16* O1   = Q;  // reuse Q after attention

  const dim3 blk(256, 1, 1);
  auto cvt = [&](const float* src, __hip_bfloat16* dst, int n) {
    f32_to_bf16<<<dim3((n + 1023) / 1024, 1, 1), blk, 0, stream>>>(src, dst, n);
  };
  cvt(x,    xb,   16384 * 512);
  cvt(ctx,  ctxb, 1024 * 768);
  cvt(Wq_w, Wqb,  1024 * 512);
  cvt(Wk_w, Wkb,  1024 * 768);
  cvt(Wv_w, Wvb,  1024 * 768);
  cvt(P1_w, P1b,  1024 * 1024);
  cvt(P2_w, P2b,  512 * 1024);

  gemm_bt<0, 0><<<dim3(128, 8, 1), blk, 0, stream>>>(xb,   Wqb, Wq_b, Q,   16384, 1024, 512);
  gemm_bt<0, 0><<<dim3(8, 8, 1),   blk, 0, stream>>>(ctxb, Wkb, Wk_b, Kp,  1024, 1024, 768);
  gemm_bt<0, 2><<<dim3(8, 8, 1),   blk, 0, stream>>>(ctxb, Wvb, Wv_b, Vt,  1024, 1024, 768);
  attn_fused<<<dim3(64, 16, 4), blk, 0, stream>>>(Q, Kp, Vt, padm, seqm, AO);
  gemm_bt<1, 0><<<dim3(128, 8, 1), blk, 0, stream>>>(AO, P1b, P1_b, O1,  16384, 1024, 1024);
  gemm_bt<0, 1><<<dim3(128, 4, 1), blk, 0, stream>>>(O1, P2b, P2_b, out, 16384, 512, 1024);
}